// Round 1
// 949.969 us; speedup vs baseline: 1.1054x; 1.1054x over previous
//
#include <hip/hip_runtime.h>
#include <hip/hip_bf16.h>
#include <stdint.h>

// Problem constants
#define BB 4
#define TT 4096
#define DD 2048
#define MM (BB*TT)   // 16384 rows
#define WC 64        // wkv chunks per sequence
#define WL 64        // wkv chunk length (WC*WL == TT)

typedef __bf16 bf16x8 __attribute__((ext_vector_type(8)));
typedef float  f32x4  __attribute__((ext_vector_type(4)));

__device__ __forceinline__ void g2l16(const void* g, void* l) {
  __builtin_amdgcn_global_load_lds(
      (const __attribute__((address_space(1))) void*)g,
      (__attribute__((address_space(3))) void*)l,
      16, 0, 0);
}

// ---------------------------------------------------------------------------
// Kernel 0: dtype detect + convert small vectors to fp32.
// ---------------------------------------------------------------------------
__global__ void detect_small_kernel(const void* __restrict__ tdec_raw,
                                    const void* __restrict__ tfirst_raw,
                                    const void* __restrict__ lng_raw,
                                    const void* __restrict__ lnb_raw,
                                    const void* __restrict__ tmk_raw,
                                    const void* __restrict__ tmv_raw,
                                    const void* __restrict__ tmr_raw,
                                    int* __restrict__ flag,
                                    float* __restrict__ tdecF,
                                    float* __restrict__ tfirstF,
                                    float* __restrict__ lngF,
                                    float* __restrict__ lnbF,
                                    float* __restrict__ tmkF,
                                    float* __restrict__ tmvF,
                                    float* __restrict__ tmrF)
{
  const uint32_t w0 = *(const uint32_t*)tdec_raw;
  const int isf32 = ((w0 & 0xFFFFu) == 0u) ? 1 : 0;
  if (threadIdx.x == 0) *flag = isf32;
  for (int d = threadIdx.x; d < DD; d += blockDim.x) {
    if (isf32) {
      tdecF[d]   = ((const float*)tdec_raw)[d];
      tfirstF[d] = ((const float*)tfirst_raw)[d];
      lngF[d]    = ((const float*)lng_raw)[d];
      lnbF[d]    = ((const float*)lnb_raw)[d];
      tmkF[d]    = ((const float*)tmk_raw)[d];
      tmvF[d]    = ((const float*)tmv_raw)[d];
      tmrF[d]    = ((const float*)tmr_raw)[d];
    } else {
      tdecF[d]   = (float)((const __bf16*)tdec_raw)[d];
      tfirstF[d] = (float)((const __bf16*)tfirst_raw)[d];
      lngF[d]    = (float)((const __bf16*)lng_raw)[d];
      lnbF[d]    = (float)((const __bf16*)lnb_raw)[d];
      tmkF[d]    = (float)((const __bf16*)tmk_raw)[d];
      tmvF[d]    = (float)((const __bf16*)tmv_raw)[d];
      tmrF[d]    = (float)((const __bf16*)tmr_raw)[d];
    }
  }
}

// ---------------------------------------------------------------------------
// Kernel 0b: convert one DxD weight matrix to canonical bf16
// ---------------------------------------------------------------------------
__global__ void convert_w_kernel(const void* __restrict__ src,
                                 __bf16* __restrict__ dst,
                                 const int* __restrict__ flagp)
{
  const int isf32 = *flagp;
  const int64_t NV = (int64_t)DD * DD / 8;
  for (int64_t v = blockIdx.x * (int64_t)blockDim.x + threadIdx.x;
       v < NV; v += (int64_t)gridDim.x * blockDim.x) {
    const int64_t i = v * 8;
    bf16x8 o;
    if (isf32) {
      const float* sf = (const float*)src;
      f32x4 a = *(const f32x4*)(sf + i);
      f32x4 b = *(const f32x4*)(sf + i + 4);
      #pragma unroll
      for (int e = 0; e < 4; e++) { o[e] = (__bf16)a[e]; o[e+4] = (__bf16)b[e]; }
    } else {
      o = *(const bf16x8*)((const __bf16*)src + i);
    }
    *(bf16x8*)(dst + i) = o;
  }
}

// ---------------------------------------------------------------------------
// Kernel 1: token-shift mix -> xk, xv, xr (bf16)
// ---------------------------------------------------------------------------
__global__ void mix_kernel(const void* __restrict__ xraw,
                           const float* __restrict__ tmkF,
                           const float* __restrict__ tmvF,
                           const float* __restrict__ tmrF,
                           const int* __restrict__ flagp,
                           __bf16* __restrict__ xk,
                           __bf16* __restrict__ xv,
                           __bf16* __restrict__ xr)
{
  const int isf32 = *flagp;
  const int64_t NV = (int64_t)MM * DD / 8;
  for (int64_t v = blockIdx.x * (int64_t)blockDim.x + threadIdx.x;
       v < NV; v += (int64_t)gridDim.x * blockDim.x) {
    const int64_t i = v * 8;
    const int d = (int)(i & (DD - 1));
    const int64_t td = i & ((int64_t)TT * DD - 1);
    const bool has_prev = (td >= DD);
    float xc[8], xp[8];
    if (isf32) {
      const float* xf = (const float*)xraw;
      f32x4 a = *(const f32x4*)(xf + i);
      f32x4 b = *(const f32x4*)(xf + i + 4);
      #pragma unroll
      for (int e = 0; e < 4; e++) { xc[e] = a[e]; xc[e+4] = b[e]; }
      if (has_prev) {
        f32x4 c = *(const f32x4*)(xf + i - DD);
        f32x4 dd4 = *(const f32x4*)(xf + i - DD + 4);
        #pragma unroll
        for (int e = 0; e < 4; e++) { xp[e] = c[e]; xp[e+4] = dd4[e]; }
      } else {
        #pragma unroll
        for (int e = 0; e < 8; e++) xp[e] = 0.f;
      }
    } else {
      const __bf16* xb = (const __bf16*)xraw;
      bf16x8 a = *(const bf16x8*)(xb + i);
      #pragma unroll
      for (int e = 0; e < 8; e++) xc[e] = (float)a[e];
      if (has_prev) {
        bf16x8 c = *(const bf16x8*)(xb + i - DD);
        #pragma unroll
        for (int e = 0; e < 8; e++) xp[e] = (float)c[e];
      } else {
        #pragma unroll
        for (int e = 0; e < 8; e++) xp[e] = 0.f;
      }
    }
    bf16x8 ok, ov, orr;
    #pragma unroll
    for (int e = 0; e < 8; e++) {
      const float diff = xc[e] - xp[e];
      ok[e]  = (__bf16)(xp[e] + tmkF[d + e] * diff);
      ov[e]  = (__bf16)(xp[e] + tmvF[d + e] * diff);
      orr[e] = (__bf16)(xp[e] + tmrF[d + e] * diff);
    }
    *(bf16x8*)(xk + i) = ok;
    *(bf16x8*)(xv + i) = ov;
    *(bf16x8*)(xr + i) = orr;
  }
}

// ---------------------------------------------------------------------------
// Kernel 2: GEMM  C[m,n] = sum_k A[m,k] * Bm[n,k]   (B^T layout, bf16 MFMA)
// 256x256 tile, BK=64, 8 waves (2Mx4N), 8-phase counted-vmcnt schedule
// (learn_hip m201 template: T2 swizzle + T3/T4 counted vmcnt + T5 setprio).
//
// LDS: 128 KiB = 2 buffers x (A 256x64 | B 256x64) bf16.
//   buf p: A at elem p*32768, B at p*32768+16384. Row stride 64 elems.
//   Swizzle (T2): 16B chunk c of row r stored at physical chunk c^(r&7).
//   global_load_lds writes linearly -> inverse swizzle on per-lane SOURCE
//   address; ds_read applies the same XOR (both-sides rule, m104/m231).
//
// Stage schedule (per K-tile pair t,t+1; tile s lives in buf[s&1]):
//   P1: rd a0,b0(buf0); stage (t+1).A0->buf1      P5: rd a0,b0(buf1); (t+2).A0->buf0
//   P2: rd b1(buf0);    stage (t+1).A1->buf1      P6: rd b1(buf1);    (t+2).A1->buf0
//   P3: rd a1(buf0);    stage (t+2).B0->buf0      P7: rd a1(buf1);    (t+3).B0->buf1
//   P4: stage (t+2).B1->buf0; vmcnt(4)            P8: (t+3).B1->buf1; vmcnt(4)
// Every stage lands strictly after the last ds_read of the region it
// overwrites (B read P1-P2, A-half0 P1/P3, A-half1 P1/P3) -> no WAR race.
// vmcnt(4) leaves exactly the next tile's B0,B1 (4 loads/wave) in flight.
// ---------------------------------------------------------------------------
#define BARX()   __builtin_amdgcn_s_barrier()
#define WAITL(n) asm volatile("s_waitcnt lgkmcnt(" #n ")" ::: "memory")
#define WAITV(n) asm volatile("s_waitcnt vmcnt(" #n ")" ::: "memory")
#define PH_PRE()  do { BARX(); WAITL(0); __builtin_amdgcn_s_setprio(1); } while (0)
#define PH_POST() do { __builtin_amdgcn_s_setprio(0); BARX(); } while (0)

#define STAGE_AH(p, h, kt) do { \
    g2l16(Asrc + (size_t)((h)*128     ) * Kd + (size_t)(kt)*64, smem + (p)*32768 + ((h)*128     )*64 + tid*8); \
    g2l16(Asrc + (size_t)((h)*128 + 64) * Kd + (size_t)(kt)*64, smem + (p)*32768 + ((h)*128 + 64)*64 + tid*8); \
  } while (0)
#define STAGE_BH(p, h, kt) do { \
    g2l16(Bsrc + (size_t)((h)*128     ) * Kd + (size_t)(kt)*64, smem + 16384 + (p)*32768 + ((h)*128     )*64 + tid*8); \
    g2l16(Bsrc + (size_t)((h)*128 + 64) * Kd + (size_t)(kt)*64, smem + 16384 + (p)*32768 + ((h)*128 + 64)*64 + tid*8); \
  } while (0)

#define RD_A0(pb) do { _Pragma("unroll") for (int i_ = 0; i_ < 4; i_++) { \
    a0[i_][0] = *(const bf16x8*)(smem + (pb) + (aoff0 + i_*1024)); \
    a0[i_][1] = *(const bf16x8*)(smem + (pb) + ((aoff0 + i_*1024) ^ 32)); } } while (0)
#define RD_A1(pb) do { _Pragma("unroll") for (int i_ = 0; i_ < 4; i_++) { \
    a1[i_][0] = *(const bf16x8*)(smem + (pb) + (aoff0 + (i_+4)*1024)); \
    a1[i_][1] = *(const bf16x8*)(smem + (pb) + ((aoff0 + (i_+4)*1024) ^ 32)); } } while (0)
#define RD_B0(pb) do { _Pragma("unroll") for (int j_ = 0; j_ < 2; j_++) { \
    b0[j_][0] = *(const bf16x8*)(smem + (pb) + (boff0 + j_*1024)); \
    b0[j_][1] = *(const bf16x8*)(smem + (pb) + ((boff0 + j_*1024) ^ 32)); } } while (0)
#define RD_B1(pb) do { _Pragma("unroll") for (int j_ = 0; j_ < 2; j_++) { \
    b1[j_][0] = *(const bf16x8*)(smem + (pb) + (boff0 + (j_+2)*1024)); \
    b1[j_][1] = *(const bf16x8*)(smem + (pb) + ((boff0 + (j_+2)*1024) ^ 32)); } } while (0)

#define MFMA16(af, bf, IO, JO) do { \
    _Pragma("unroll") for (int i_ = 0; i_ < 4; i_++) { \
    _Pragma("unroll") for (int j_ = 0; j_ < 2; j_++) { \
      acc[(IO)+i_][(JO)+j_] = __builtin_amdgcn_mfma_f32_16x16x32_bf16((af)[i_][0], (bf)[j_][0], acc[(IO)+i_][(JO)+j_], 0, 0, 0); \
      acc[(IO)+i_][(JO)+j_] = __builtin_amdgcn_mfma_f32_16x16x32_bf16((af)[i_][1], (bf)[j_][1], acc[(IO)+i_][(JO)+j_], 0, 0, 0); \
    } } } while (0)

template <int EPI>
__global__ void __launch_bounds__(512, 2)
gemm_bt(const __bf16* __restrict__ A,
        const __bf16* __restrict__ Bm,
        void* __restrict__ Cout,
        const int* __restrict__ flagp,
        int Md, int Nd, int Kd)
{
  __shared__ __bf16 smem[65536];   // 128 KiB
  const int isf32 = (EPI == 1) ? *flagp : 0;
  const int tid  = threadIdx.x;    // 0..511
  const int lane = tid & 63;
  const int wv   = tid >> 6;       // 0..7
  const int wm   = wv >> 2;        // wave row 0..1 (128 rows each)
  const int wn   = wv & 3;         // wave col 0..3 (64 cols each)
  const int l16  = lane & 15;
  const int qd   = lane >> 4;

  // XCD-aware mapping (Nd == 2048 -> 8 col-blocks == 8 XCDs; bid%8 is the
  // default XCD round-robin, so each XCD keeps one 1-MiB B panel L2-resident).
  const int bid    = blockIdx.x;
  const int colblk = bid & 7;
  const int rowblk = bid >> 3;
  const int row0   = rowblk * 256;
  const int col0   = colblk * 256;

  // staging constants: wave wv stages rows wv*8+(lane>>3), chunk lane&7,
  // source chunk inverse-swizzled so linear LDS dest holds swizzled layout.
  const int srow   = (wv << 3) + (lane >> 3);
  const int schunk = (lane & 7) ^ (lane >> 3);
  const __bf16* Asrc = A  + (size_t)(row0 + srow) * Kd + schunk * 8;
  const __bf16* Bsrc = Bm + (size_t)(col0 + srow) * Kd + schunk * 8;

  // ds_read bases (buf-relative elem offsets), chunk swizzled by row&7 = l16&7
  const int c0    = (qd ^ (l16 & 7)) * 8;
  const int aoff0 = (wm * 128 + l16) * 64 + c0;           // i=0, kk=0
  const int boff0 = 16384 + (wn * 64 + l16) * 64 + c0;    // j=0, kk=0

  f32x4 acc[8][4];
  #pragma unroll
  for (int i = 0; i < 8; i++)
    #pragma unroll
    for (int j = 0; j < 4; j++)
      acc[i][j] = (f32x4){0.f, 0.f, 0.f, 0.f};

  bf16x8 a0[4][2], a1[4][2], b0[2][2], b1[2][2];

  // Prologue: tile0 fully + tile1.B0/B1; vmcnt(4) -> tile0 resident,
  // tile1's 4 B-loads stay in flight (steady-state invariant).
  STAGE_AH(0, 0, 0); STAGE_AH(0, 1, 0);
  STAGE_BH(0, 0, 0); STAGE_BH(0, 1, 0);
  STAGE_BH(1, 0, 1); STAGE_BH(1, 1, 1);
  WAITV(4);
  BARX();

  const int npair = Kd >> 7;       // K-tile pairs
  #pragma unroll 1
  for (int it = 0; it < npair - 1; ++it) {
    const int t = it << 1;
    // ---- tile t (buf0) ----
    RD_A0(0); RD_B0(0);
    STAGE_AH(1, 0, t + 1);
    WAITL(8);
    PH_PRE(); MFMA16(a0, b0, 0, 0); PH_POST();

    RD_B1(0);
    STAGE_AH(1, 1, t + 1);
    PH_PRE(); MFMA16(a0, b1, 0, 2); PH_POST();

    RD_A1(0);
    STAGE_BH(0, 0, t + 2);
    PH_PRE(); MFMA16(a1, b1, 4, 2); PH_POST();

    STAGE_BH(0, 1, t + 2);
    WAITV(4);
    PH_PRE(); MFMA16(a1, b0, 4, 0); PH_POST();

    // ---- tile t+1 (buf1) ----
    RD_A0(32768); RD_B0(32768);
    STAGE_AH(0, 0, t + 2);
    WAITL(8);
    PH_PRE(); MFMA16(a0, b0, 0, 0); PH_POST();

    RD_B1(32768);
    STAGE_AH(0, 1, t + 2);
    PH_PRE(); MFMA16(a0, b1, 0, 2); PH_POST();

    RD_A1(32768);
    STAGE_BH(1, 0, t + 3);
    PH_PRE(); MFMA16(a1, b1, 4, 2); PH_POST();

    STAGE_BH(1, 1, t + 3);
    WAITV(4);
    PH_PRE(); MFMA16(a1, b0, 4, 0); PH_POST();
  }

  // ---- final pair (t = ntile-2, ntile-1): stage only tile ntile-1's A,
  // drain with vmcnt(0) once at the boundary. ----
  {
    const int t = (Kd >> 6) - 2;
    RD_A0(0); RD_B0(0);
    STAGE_AH(1, 0, t + 1);
    WAITL(8);
    PH_PRE(); MFMA16(a0, b0, 0, 0); PH_POST();

    RD_B1(0);
    STAGE_AH(1, 1, t + 1);
    PH_PRE(); MFMA16(a0, b1, 0, 2); PH_POST();

    RD_A1(0);
    PH_PRE(); MFMA16(a1, b1, 4, 2); PH_POST();

    WAITV(0);
    PH_PRE(); MFMA16(a1, b0, 4, 0); PH_POST();

    RD_A0(32768); RD_B0(32768);
    WAITL(8);
    PH_PRE(); MFMA16(a0, b0, 0, 0); PH_POST();

    RD_B1(32768);
    PH_PRE(); MFMA16(a0, b1, 0, 2); PH_POST();

    RD_A1(32768);
    PH_PRE(); MFMA16(a1, b1, 4, 2); PH_POST();

    PH_PRE(); MFMA16(a1, b0, 4, 0); __builtin_amdgcn_s_setprio(0);
  }

  // epilogue: C/D layout col=lane&15, row=quad*4+reg (verified m89/m91)
  #pragma unroll
  for (int i = 0; i < 8; i++) {
    const int rb = row0 + wm * 128 + i * 16 + qd * 4;
    #pragma unroll
    for (int j = 0; j < 4; j++) {
      const int c = col0 + wn * 64 + j * 16 + l16;
      #pragma unroll
      for (int reg = 0; reg < 4; reg++) {
        const size_t idx = (size_t)(rb + reg) * Nd + c;
        float v = acc[i][j][reg];
        if (EPI == 0) {
          ((float*)Cout)[idx] = v;
        } else if (EPI == 1) {
          if (isf32) ((float*)Cout)[idx] = v;
          else       ((__bf16*)Cout)[idx] = (__bf16)v;
        } else {
          float s = 1.f / (1.f + __expf(-v));
          ((__bf16*)Cout)[idx] = (__bf16)s;
        }
      }
    }
  }
}

// ---------------------------------------------------------------------------
// WKV as a parallel log-sum-exp prefix sum (unchanged).
// ---------------------------------------------------------------------------
__global__ void wkv_part_kernel(const float* __restrict__ Kb,
                                const float* __restrict__ Vb,
                                float* __restrict__ pM,
                                float* __restrict__ pA,
                                float* __restrict__ pB)
{
  const int gid = blockIdx.x * blockDim.x + threadIdx.x;
  const int d = gid & (DD - 1);
  const int rest = gid >> 11;
  const int c = rest & (WC - 1);
  const int b = rest >> 6;
  const float* kp = Kb + ((size_t)b * TT + (size_t)c * WL) * DD + d;
  const float* vp = Vb + ((size_t)b * TT + (size_t)c * WL) * DD + d;
  float M = -1e38f, A = 0.f, Bv = 0.f;
  for (int t = 0; t < WL; t++) {
    const float k = kp[(size_t)t * DD];
    const float v = vp[(size_t)t * DD];
    const float q = fmaxf(M, k);
    const float s = __expf(M - q);
    const float e = __expf(k - q);
    A = A * s + e * v;
    Bv = Bv * s + e;
    M = q;
  }
  const size_t pi = ((size_t)b * WC + c) * DD + d;
  pM[pi] = M; pA[pi] = A; pB[pi] = Bv;
}

__global__ void wkv_scan_kernel(float* __restrict__ pM,
                                float* __restrict__ pA,
                                float* __restrict__ pB)
{
  const int gid = blockIdx.x * blockDim.x + threadIdx.x;
  const int d = gid & (DD - 1);
  const int b = gid >> 11;
  float M = -1e38f, A = 0.f, Bv = 0.f;
  for (int c = 0; c < WC; c++) {
    const size_t pi = ((size_t)b * WC + c) * DD + d;
    const float m = pM[pi], a = pA[pi], bb = pB[pi];
    pM[pi] = M; pA[pi] = A; pB[pi] = Bv;
    const float q = fmaxf(M, m);
    const float s0 = __expf(M - q);
    const float s1 = __expf(m - q);
    A = A * s0 + a * s1;
    Bv = Bv * s0 + bb * s1;
    M = q;
  }
}

__global__ void wkv_out_kernel(const float* __restrict__ Kb,
                               const float* __restrict__ Vb,
                               const float* __restrict__ pM,
                               const float* __restrict__ pA,
                               const float* __restrict__ pB,
                               const float* __restrict__ tfirstF,
                               float* __restrict__ out)
{
  const int gid = blockIdx.x * blockDim.x + threadIdx.x;
  const int d = gid & (DD - 1);
  const int rest = gid >> 11;
  const int c = rest & (WC - 1);
  const int b = rest >> 6;
  const size_t pi = ((size_t)b * WC + c) * DD + d;
  float M = pM[pi], A = pA[pi], Bv = pB[pi];
  const float u = tfirstF[d];
  const size_t base = ((size_t)b * TT + (size_t)c * WL) * DD + d;
  const float* kp = Kb + base;
  const float* vp = Vb + base;
  float*       op = out + base;
  for (int t = 0; t < WL; t++) {
    const float k = kp[(size_t)t * DD];
    const float v = vp[(size_t)t * DD];
    const float ku = k + u;
    const float qo = fmaxf(M, ku);
    const float so = __expf(M - qo);
    const float eo = __expf(ku - qo);
    op[(size_t)t * DD] = __fdividef(A * so + v * eo, Bv * so + eo);
    const float q = fmaxf(M, k);
    const float s = __expf(M - q);
    const float e = __expf(k - q);
    A = A * s + e * v;
    Bv = Bv * s + e;
    M = q;
  }
}

// ---------------------------------------------------------------------------
// Kernel 4: LayerNorm over D + multiply by r -> rwkv (bf16) (unchanged)
// ---------------------------------------------------------------------------
__global__ void ln_kernel(const float* __restrict__ wkv,
                          const __bf16* __restrict__ rbuf,
                          const float* __restrict__ g,
                          const float* __restrict__ beta,
                          __bf16* __restrict__ out)
{
  const int row = blockIdx.x;
  const int tid = threadIdx.x;
  const float* xr = wkv + (size_t)row * DD;

  float vals[8];
  float s = 0.f, sq = 0.f;
  #pragma unroll
  for (int j = 0; j < 8; j++) {
    float v = xr[tid + j * 256];
    vals[j] = v;
    s += v;
    sq += v * v;
  }
  #pragma unroll
  for (int off = 1; off < 64; off <<= 1) {
    s  += __shfl_xor(s, off);
    sq += __shfl_xor(sq, off);
  }
  __shared__ float ls[4], lsq[4];
  const int wave = tid >> 6;
  if ((tid & 63) == 0) { ls[wave] = s; lsq[wave] = sq; }
  __syncthreads();
  s  = ls[0] + ls[1] + ls[2] + ls[3];
  sq = lsq[0] + lsq[1] + lsq[2] + lsq[3];

  const float mu = s * (1.f / DD);
  const float var = sq * (1.f / DD) - mu * mu;
  const float rs = rsqrtf(var + 1e-5f);

  #pragma unroll
  for (int j = 0; j < 8; j++) {
    const int dcol = tid + j * 256;
    const size_t idx = (size_t)row * DD + dcol;
    float v = (vals[j] - mu) * rs * g[dcol] + beta[dcol];
    float rr = (float)rbuf[idx];
    out[idx] = (__bf16)(rr * v);
  }
}

// ---------------------------------------------------------------------------
extern "C" void kernel_launch(void* const* d_in, const int* in_sizes, int n_in,
                              void* d_out, int out_size, void* d_ws, size_t ws_size,
                              hipStream_t stream) {
  const void* x      = d_in[0];
  const void* Wk     = d_in[1];
  const void* Wv     = d_in[2];
  const void* Wr     = d_in[3];
  const void* Wo     = d_in[4];
  const void* tmk    = d_in[5];
  const void* tmv    = d_in[6];
  const void* tmr    = d_in[7];
  const void* tdec   = d_in[8];
  const void* tfirst = d_in[9];
  const void* lng    = d_in[10];
  const void* lnb    = d_in[11];

  char* ws = (char*)d_ws;
  const size_t SZ_BF = (size_t)MM * DD * 2;   // 64 MiB
  const size_t SZ_F  = (size_t)MM * DD * 4;   // 128 MiB
  const size_t SZ_W  = (size_t)DD * DD * 2;   // 8 MiB
  __bf16* XK   = (__bf16*)(ws);
  __bf16* XV   = (__bf16*)(ws + SZ_BF);
  __bf16* XR   = (__bf16*)(ws + 2 * SZ_BF);
  float*  Kb   = (float*)(ws + 3 * SZ_BF);
  float*  Vb   = (float*)(ws + 3 * SZ_BF + SZ_F);
  __bf16* WkB  = (__bf16*)(ws + 3 * SZ_BF + 2 * SZ_F);
  __bf16* WvB  = (__bf16*)(ws + 3 * SZ_BF + 2 * SZ_F + SZ_W);
  __bf16* WrB  = (__bf16*)(ws + 3 * SZ_BF + 2 * SZ_F + 2 * SZ_W);
  __bf16* WoB  = (__bf16*)(ws + 3 * SZ_BF + 2 * SZ_F + 3 * SZ_W);
  char*   smal = ws + 3 * SZ_BF + 2 * SZ_F + 4 * SZ_W;
  int*    flag    = (int*)smal;
  float*  tdecF   = (float*)(smal + 64);
  float*  tfirstF = tdecF + DD;
  float*  lngF    = tdecF + 2 * DD;
  float*  lnbF    = tdecF + 3 * DD;
  float*  tmkF    = tdecF + 4 * DD;
  float*  tmvF    = tdecF + 5 * DD;
  float*  tmrF    = tdecF + 6 * DD;
  float*  Wkv  = (float*)(ws);                 // over XK+XV (dead after GEMMs)
  __bf16* Rwkv = (__bf16*)(ws + 2 * SZ_BF);    // over XR
  __bf16* Rb   = (__bf16*)d_out;               // d_out as scratch until final GEMM
  float* pM = (float*)(ws + 2 * SZ_BF);
  float* pA = pM + (size_t)BB * WC * DD;
  float* pB = pA + (size_t)BB * WC * DD;

  detect_small_kernel<<<dim3(1), dim3(256), 0, stream>>>(
      tdec, tfirst, lng, lnb, tmk, tmv, tmr,
      flag, tdecF, tfirstF, lngF, lnbF, tmkF, tmvF, tmrF);

  convert_w_kernel<<<dim3(512), dim3(256), 0, stream>>>(Wk, WkB, flag);
  convert_w_kernel<<<dim3(512), dim3(256), 0, stream>>>(Wv, WvB, flag);
  convert_w_kernel<<<dim3(512), dim3(256), 0, stream>>>(Wr, WrB, flag);
  convert_w_kernel<<<dim3(512), dim3(256), 0, stream>>>(Wo, WoB, flag);

  mix_kernel<<<dim3(4096), dim3(256), 0, stream>>>(x, tmkF, tmvF, tmrF, flag, XK, XV, XR);

  dim3 g((MM / 256) * (DD / 256));   // 512 blocks: colblk = bid&7, rowblk = bid>>3
  dim3 blk(512);
  gemm_bt<0><<<g, blk, 0, stream>>>(XK, WkB, (void*)Kb, flag, MM, DD, DD);
  gemm_bt<0><<<g, blk, 0, stream>>>(XV, WvB, (void*)Vb, flag, MM, DD, DD);
  gemm_bt<2><<<g, blk, 0, stream>>>(XR, WrB, (void*)Rb, flag, MM, DD, DD);

  wkv_part_kernel<<<dim3((BB * DD * WC) / 256), dim3(256), 0, stream>>>(Kb, Vb, pM, pA, pB);
  wkv_scan_kernel<<<dim3((BB * DD) / 256), dim3(256), 0, stream>>>(pM, pA, pB);
  wkv_out_kernel<<<dim3((BB * DD * WC) / 256), dim3(256), 0, stream>>>(Kb, Vb, pM, pA, pB, tfirstF, Wkv);

  ln_kernel<<<dim3(MM), dim3(256), 0, stream>>>(Wkv, Rb, lngF, lnbF, Rwkv);

  gemm_bt<1><<<g, blk, 0, stream>>>(Rwkv, WoB, d_out, flag, MM, DD, DD);
}